// Round 3
// baseline (182.123 us; speedup 1.0000x reference)
//
#include <hip/hip_runtime.h>
#include <hip/hip_bf16.h>

// corr via MFMA band extraction:
// out[b,(di+4)*9+(dj+4),h,w] = sum_c x[b,c,h,w] * y[b,c,refl(h+di),refl(w+dj)]
// A = Y_bf16[w'-tile, c], B = X_bf16[c, w-tile]; D[w',w] diagonals = dj.

#define HH   256
#define WW   256
#define CCH  64
#define KRAD 4
#define ND   81

#define WT   16                 // output w per block
#define HT   16                 // output h per block
#define WY   24                 // staged y width = WT + 2*KRAD
#define RSTRIDE 144             // bytes per (row,w'): 64c*2B + 16B pad
#define YRING 10
#define YSLOT (WY * RSTRIDE)    // 3456 B

typedef __attribute__((ext_vector_type(8))) short bf16x8;
typedef __attribute__((ext_vector_type(4))) float f32x4;

__device__ __forceinline__ int reflect(int v, int n) {
    v = v < 0 ? -v : v;
    return v >= n ? 2 * n - 2 - v : v;
}
__device__ __forceinline__ unsigned f2bf_pk(float a, float b) {
    union { float f; unsigned u; } xa, xb;
    xa.f = a; xb.f = b;
    unsigned ra = (xa.u + 0x7fffu + ((xa.u >> 16) & 1u)) >> 16;
    unsigned rb = (xb.u + 0x7fffu + ((xb.u >> 16) & 1u)) >> 16;
    return ra | (rb << 16);
}
__device__ __forceinline__ int mod10(int s) {   // s in [0, 30)
    if (s >= 20) s -= 20; else if (s >= 10) s -= 10;
    return s;
}

__global__ __launch_bounds__(256, 4) void corr_mfma_kernel(
    const float* __restrict__ x, const float* __restrict__ y,
    float* __restrict__ out)
{
    __shared__ char ylds[YRING * YSLOT];   // 34560 B -> 4 blocks/CU

    // XCD-chunked bijective swizzle: 1024 blocks = 8 XCDs * 128
    const int d  = blockIdx.x;
    const int v  = (d & 7) * 128 + (d >> 3);
    const int b  = v >> 8;
    const int by = (v >> 4) & 15;
    const int bx = v & 15;
    const int w0 = bx * WT;
    const int h0 = by * HT;

    const int t    = threadIdx.x;
    const int wid  = t >> 6;
    const int lane = t & 63;
    const int lq   = lane >> 4;      // 0..3
    const int ln   = lane & 15;      // 0..15

    const size_t plane = (size_t)HH * WW;
    const float* yb = y + (size_t)b * CCH * plane;
    const float* xb = x + (size_t)b * CCH * plane;

    // staging lane mapping for Y rows
    const int yp  = t & 31;          // w' position, active < WY
    const int ycg = t >> 5;          // c group: c = 8*ycg + j

    auto loadY = [&](int hrow, float* v8) {
        int gh = reflect(hrow, HH);
        int pc = yp < WY ? yp : WY - 1;
        int gw = reflect(w0 - KRAD + pc, WW);
        const float* src = yb + (size_t)(ycg * 8) * plane + (size_t)gh * WW + gw;
#pragma unroll
        for (int j = 0; j < 8; ++j) v8[j] = src[(size_t)j * plane];
    };
    auto writeY = [&](int slot, const float* v8) {
        if (yp < WY) {
            char* dst = ylds + slot * YSLOT + yp * RSTRIDE + ycg * 16;
#pragma unroll
            for (int m = 0; m < 4; ++m)
                *(unsigned*)(dst + 4 * m) = f2bf_pk(v8[2 * m], v8[2 * m + 1]);
        }
    };
    // X direct-to-register: lane (lq,ln) holds B[c = lq*8+j (+32), w0+ln]
    auto loadX = [&](int hrow, float* v16) {
        int gh = reflect(hrow, HH);
        const float* src = xb + (size_t)(lq * 8) * plane + (size_t)gh * WW + (w0 + ln);
#pragma unroll
        for (int j = 0; j < 8; ++j) v16[j] = src[(size_t)j * plane];
        const float* src2 = src + (size_t)32 * plane;
#pragma unroll
        for (int j = 0; j < 8; ++j) v16[8 + j] = src2[(size_t)j * plane];
    };
    auto xconv = [&](const float* v16, bf16x8& f0, bf16x8& f1) {
        union { unsigned u[4]; bf16x8 v; } c0, c1;
#pragma unroll
        for (int m = 0; m < 4; ++m) {
            c0.u[m] = f2bf_pk(v16[2 * m], v16[2 * m + 1]);
            c1.u[m] = f2bf_pk(v16[8 + 2 * m], v16[9 + 2 * m]);
        }
        f0 = c0.v; f1 = c1.v;
    };

    float yv[8], yv2[8], xv[16];
    bf16x8 bf0, bf1;

    // ---- prologue: Y rows h0-4..h0+4 -> slots 0..8 (2-stage pipelined) ----
    loadY(h0 - KRAD, yv);
    loadX(h0, xv);
#pragma unroll 1
    for (int j = 0; j < 9; ++j) {
        if (j < 8) loadY(h0 - KRAD + j + 1, yv2);
        writeY(j, yv);
#pragma unroll
        for (int m = 0; m < 8; ++m) yv[m] = yv2[m];
    }
    xconv(xv, bf0, bf1);
    __syncthreads();

    // ---- main loop over h ----
#pragma unroll 1
    for (int hh = 0; hh < HT; ++hh) {
        const int h = h0 + hh;

        // issue next-iteration global loads early
        loadY(h + KRAD + 1, yv);
        loadX(h + 1, xv);

        float* outb = out + (size_t)b * ND * plane + (size_t)h * WW + (w0 + ln);

        // 18 (di,wt) units split across 4 waves: 5/5/4/4
        for (int u = wid; u < 18; u += 4) {
            const int di = u >> 1;
            const int wt = u & 1;
            const int slot = mod10(hh + di);
            const char* ab = ylds + slot * YSLOT + (wt * 16 + 0) * RSTRIDE
                           + ln * RSTRIDE + lq * 16;
            bf16x8 af0 = *(const bf16x8*)(ab);
            bf16x8 af1 = *(const bf16x8*)(ab + 64);
            f32x4 dacc = {0.f, 0.f, 0.f, 0.f};
            dacc = __builtin_amdgcn_mfma_f32_16x16x32_bf16(af0, bf0, dacc, 0, 0, 0);
            dacc = __builtin_amdgcn_mfma_f32_16x16x32_bf16(af1, bf1, dacc, 0, 0, 0);
#pragma unroll
            for (int r = 0; r < 4; ++r) {
                int m  = lq * 4 + r;                 // w' row of D
                int dj = m - ln + (wt ? 12 : -KRAD); // displacement
                if ((unsigned)(dj + KRAD) <= 2u * KRAD) {
                    int didx = di * 9 + (dj + KRAD);
                    __builtin_nontemporal_store(dacc[r], &outb[(size_t)didx * plane]);
                }
            }
        }

        // stage next Y row (slot was last read at iter hh-1; barrier protected)
        writeY(mod10(hh + 9), yv);
        xconv(xv, bf0, bf1);
        __syncthreads();
    }
}

extern "C" void kernel_launch(void* const* d_in, const int* in_sizes, int n_in,
                              void* d_out, int out_size, void* d_ws, size_t ws_size,
                              hipStream_t stream) {
    const float* x = (const float*)d_in[0];
    const float* y = (const float*)d_in[1];
    float* out = (float*)d_out;

    dim3 grid(1024);   // 16 w-tiles * 16 h-tiles * 4 batch, XCD-swizzled in-kernel
    dim3 block(256);
    corr_mfma_kernel<<<grid, block, 0, stream>>>(x, y, out);
}

// Round 4
// 86.371 us; speedup vs baseline: 2.1086x; 2.1086x over previous
//
#include <hip/hip_runtime.h>
#include <hip/hip_bf16.h>

// corr via MFMA band extraction:
// out[b,(di+4)*9+(dj+4),h,w] = sum_c x[b,c,h,w] * y[b,c,refl(h+di),refl(w+dj)]
// A = Y_bf16[w'-tile, c], B = X_bf16[c, w-tile]; D[w',w] diagonals = dj.

#define HH   256
#define WW   256
#define CCH  64
#define KRAD 4
#define ND   81

#define WT   16                 // output w per block
#define HT   16                 // output h per block
#define WY   24                 // staged y width = WT + 2*KRAD
#define RSTRIDE 128             // bytes per (row,w'): 64c*2B, XOR-swizzled chunks
#define YRING 10
#define YSLOT (WY * RSTRIDE)    // 3072 B

typedef __attribute__((ext_vector_type(8))) short bf16x8;
typedef __attribute__((ext_vector_type(4))) float f32x4;

__device__ __forceinline__ int reflect(int v, int n) {
    v = v < 0 ? -v : v;
    return v >= n ? 2 * n - 2 - v : v;
}
__device__ __forceinline__ unsigned f2bf_pk(float a, float b) {
    union { float f; unsigned u; } xa, xb;
    xa.f = a; xb.f = b;
    unsigned ra = (xa.u + 0x7fffu + ((xa.u >> 16) & 1u)) >> 16;
    unsigned rb = (xb.u + 0x7fffu + ((xb.u >> 16) & 1u)) >> 16;
    return ra | (rb << 16);
}
__device__ __forceinline__ int mod10(int s) {   // s in [0, 30)
    if (s >= 20) s -= 20; else if (s >= 10) s -= 10;
    return s;
}

__global__ __launch_bounds__(256, 5) void corr_mfma_kernel(
    const float* __restrict__ x, const float* __restrict__ y,
    float* __restrict__ out)
{
    __shared__ char ylds[YRING * YSLOT];   // 30720 B -> 5 blocks/CU

    // XCD-chunked bijective swizzle: 1024 blocks = 8 XCDs * 128
    const int d  = blockIdx.x;
    const int v  = (d & 7) * 128 + (d >> 3);
    const int b  = v >> 8;
    const int by = (v >> 4) & 15;
    const int bx = v & 15;
    const int w0 = bx * WT;
    const int h0 = by * HT;

    const int t    = threadIdx.x;
    const int wid  = t >> 6;
    const int lane = t & 63;
    const int lq   = lane >> 4;      // 0..3
    const int ln   = lane & 15;      // 0..15

    const size_t plane = (size_t)HH * WW;
    const float* yb = y + (size_t)b * CCH * plane;
    const float* xb = x + (size_t)b * CCH * plane;

    // staging lane mapping for Y rows
    const int yp  = t & 31;          // w' position, active < WY
    const int ycg = t >> 5;          // c group: c = 8*ycg + j

    auto loadY = [&](int hrow, float* v8) {
        int gh = reflect(hrow, HH);
        int pc = yp < WY ? yp : WY - 1;
        int gw = reflect(w0 - KRAD + pc, WW);
        const float* src = yb + (size_t)(ycg * 8) * plane + (size_t)gh * WW + gw;
#pragma unroll
        for (int j = 0; j < 8; ++j) v8[j] = src[(size_t)j * plane];
    };
    auto writeY = [&](int slot, const float* v8) {
        if (yp < WY) {
            // XOR chunk-swizzle: 16B chunk index ^= (row & 7)
            char* dst = ylds + slot * YSLOT + yp * RSTRIDE
                      + (((unsigned)(ycg * 16)) ^ ((unsigned)(yp & 7) << 4));
            union { unsigned u[4]; uint4 q; } pk;
#pragma unroll
            for (int m = 0; m < 4; ++m)
                pk.u[m] = f2bf_pk(v8[2 * m], v8[2 * m + 1]);
            *(uint4*)dst = pk.q;
        }
    };
    // X direct-to-register: lane (lq,ln) holds B[c = lq*8+j (+32), w0+ln]
    auto loadX = [&](int hrow, float* v16) {
        int gh = reflect(hrow, HH);
        const float* src = xb + (size_t)(lq * 8) * plane + (size_t)gh * WW + (w0 + ln);
#pragma unroll
        for (int j = 0; j < 8; ++j) v16[j] = src[(size_t)j * plane];
        const float* src2 = src + (size_t)32 * plane;
#pragma unroll
        for (int j = 0; j < 8; ++j) v16[8 + j] = src2[(size_t)j * plane];
    };
    auto xconv = [&](const float* v16, bf16x8& f0, bf16x8& f1) {
        union { unsigned u[4]; bf16x8 v; } c0, c1;
#pragma unroll
        for (int m = 0; m < 4; ++m) {
            c0.u[m] = f2bf_pk(v16[2 * m], v16[2 * m + 1]);
            c1.u[m] = f2bf_pk(v16[8 + 2 * m], v16[9 + 2 * m]);
        }
        f0 = c0.v; f1 = c1.v;
    };

    float yv[8], yv2[8], xv[16];
    bf16x8 bf0, bf1;

    // ---- prologue: Y rows h0-4..h0+4 -> slots 0..8 (2-stage pipelined) ----
    loadY(h0 - KRAD, yv);
    loadX(h0, xv);
#pragma unroll 1
    for (int j = 0; j < 9; ++j) {
        if (j < 8) loadY(h0 - KRAD + j + 1, yv2);
        writeY(j, yv);
#pragma unroll
        for (int m = 0; m < 8; ++m) yv[m] = yv2[m];
    }
    xconv(xv, bf0, bf1);
    __syncthreads();

    // ---- main loop over h ----
#pragma unroll 1
    for (int hh = 0; hh < HT; ++hh) {
        const int h = h0 + hh;

        // issue next-iteration global loads early
        loadY(h + KRAD + 1, yv);
        loadX(h + 1, xv);

        float* outb = out + (size_t)b * ND * plane + (size_t)h * WW + (w0 + ln);

        // 18 (di,wt) units split across 4 waves: 5/5/4/4
        for (int u = wid; u < 18; u += 4) {
            const int di = u >> 1;
            const int wt = u & 1;
            const int slot = mod10(hh + di);
            const char* abase = ylds + slot * YSLOT + (wt * 16 + ln) * RSTRIDE;
            const unsigned sw = (unsigned)(ln & 7) << 4;
            bf16x8 af0 = *(const bf16x8*)(abase + (((unsigned)(lq * 16)) ^ sw));
            bf16x8 af1 = *(const bf16x8*)(abase + (((unsigned)(64 + lq * 16)) ^ sw));
            f32x4 dacc = {0.f, 0.f, 0.f, 0.f};
            dacc = __builtin_amdgcn_mfma_f32_16x16x32_bf16(af0, bf0, dacc, 0, 0, 0);
            dacc = __builtin_amdgcn_mfma_f32_16x16x32_bf16(af1, bf1, dacc, 0, 0, 0);
#pragma unroll
            for (int r = 0; r < 4; ++r) {
                int m  = lq * 4 + r;                 // w' row of D
                int dj = m - ln + (wt ? 12 : -KRAD); // displacement
                if ((unsigned)(dj + KRAD) <= 2u * KRAD) {
                    int didx = di * 9 + (dj + KRAD);
                    outb[(size_t)didx * plane] = dacc[r];
                }
            }
        }

        // stage next Y row (slot was retired; barrier-protected)
        writeY(mod10(hh + 9), yv);
        xconv(xv, bf0, bf1);
        __syncthreads();
    }
}

extern "C" void kernel_launch(void* const* d_in, const int* in_sizes, int n_in,
                              void* d_out, int out_size, void* d_ws, size_t ws_size,
                              hipStream_t stream) {
    const float* x = (const float*)d_in[0];
    const float* y = (const float*)d_in[1];
    float* out = (float*)d_out;

    dim3 grid(1024);   // 16 w-tiles * 16 h-tiles * 4 batch, XCD-swizzled in-kernel
    dim3 block(256);
    corr_mfma_kernel<<<grid, block, 0, stream>>>(x, y, out);
}